// Round 14
// baseline (151.980 us; speedup 1.0000x reference)
//
#include <hip/hip_runtime.h>

// BSScanThru: out = brev8( (brev8(a) + brev8(b) + carry-chain) mod 256 ) & ~b
//
// Wave-decoupled single pass, perfectly-coalesced accesses, wave tile 2048.
//
// Geometry (r13 win, kept): wave tile split into NCHUNK chunks of 256
// elems; in chunk q, lane l owns elems q*256 + l*4 .. +3 -> every
// load/store instruction is 64 lanes x 16B contiguous (16 fully-used
// lines). r14 change: NCHUNK 4 -> 8 (wave tile 1024 -> 2048): halves
// peek frequency and per-tile address setup; per-instruction geometry
// unchanged (r10's strided-span regression does not apply).
//
// Carry-lookahead identity: p_j = (c_j==255) implies g_j = 0, so carry
// into any position = g of the nearest preceding element with c != 255.
// Each wave peeks backward once from its tile base (64-elem window,
// ballot c!=255, g of highest lane; step back on all-propagate, prob
// ~2^-512; idx<0 acts as {c=0,g=0} -> array start needs no special case).
//
// Adder trick (g,p disjoint => carry chain of G+(G|P)+cin IS the gp
// recurrence; carry into bit k = P_k ^ S_k):
//   4-elem group:  Cm = P ^ (G + (G|P) + c_t)      (4-bit masks)
//   wave chunk:    c_t = bit lane of Pw ^ (Gw + (Gw|Pw) + cb)
//   chunk chain:   cb' = carry-out of the 64-bit add (in-register).
//
// Ledger: coalesced chunks +4% (r13). Neutral: occupancy (r9), sync
// removal (r11), SW pipeline (r12). Negative: nt stores (r7, WRITE +66%),
// XCD swizzle (r8, broke L3 locality), 64B-strided EPT=32 (r10).
//
// Inputs: int32 (values 0..255). Output: int32.

#define BLK 256
#define CHUNK 256            // elems per chunk: 64 lanes x 4
#define NCHUNK 8
#define WTILE (CHUNK * NCHUNK)  // 2048 elems per wave
#define WAVES (BLK / 64)

typedef int iv4 __attribute__((ext_vector_type(4)));

__device__ __forceinline__ unsigned brev8(unsigned x) {
    return __brev(x) >> 24;
}

__global__ __launch_bounds__(BLK) void bss_coal(const int* __restrict__ a,
                                                const int* __restrict__ b,
                                                int* __restrict__ out) {
    const int tid = threadIdx.x;
    const int lane = tid & 63;
    const int wid = tid >> 6;
    const long w0 = ((long)blockIdx.x * WAVES + wid) * WTILE;  // wave tile base

    // ---- main tile loads issued FIRST: 16 perfectly-contiguous dwordx4 ----
    iv4 av[NCHUNK], bv[NCHUNK];
#pragma unroll
    for (int q = 0; q < NCHUNK; ++q) {
        const int off = (int)w0 + q * CHUNK + lane * 4;
        av[q] = *reinterpret_cast<const iv4*>(a + off);
        bv[q] = *reinterpret_cast<const iv4*>(b + off);
    }

    // ---- wave carry-in via backward peek (once per 2048 elems) ----
    unsigned cb = 0u;
    {
        long w = w0 - 64;
        for (;;) {
            long idx = w + lane;
            unsigned cc = 0u, gg = 0u;   // idx < 0: virtual non-propagating, g=0
            if (idx >= 0) {
                unsigned s = brev8((unsigned)a[idx]) + brev8((unsigned)b[idx]);
                cc = s & 0xFFu;
                gg = s >> 8;
            }
            unsigned long long m = __ballot(cc != 0xFFu);
            if (m) {
                int hi = 63 - __clzll(m);        // nearest to tile base
                cb = (unsigned)__shfl((int)gg, hi, 64);
                break;
            }
            w -= 64;
        }
    }

    // ---- 8 chunks, carry chained in-register across ballot-adder chains ----
#pragma unroll
    for (int q = 0; q < NCHUNK; ++q) {
        unsigned c[4], G = 0u, P = 0u;
#pragma unroll
        for (int j = 0; j < 4; ++j) {
            unsigned s = brev8((unsigned)av[q][j]) + brev8((unsigned)bv[q][j]);
            c[j] = s & 0xFFu;
            G |= (s >> 8) << j;               // carry generated
            P |= ((c[j] + 1u) >> 8) << j;     // 1 iff c[j]==255
        }
        const unsigned GoP = G | P;
        const unsigned g_t = (G + GoP) >> 4;            // 4-elem carry-out (cin=0)
        const unsigned p_t = (P == 0xFu) ? 1u : 0u;

        const unsigned long long Gw = __ballot(g_t != 0u);
        const unsigned long long Pw = __ballot(p_t != 0u);
        const unsigned long long T  = Gw + (Gw | Pw);
        const unsigned long long Sw = T + (unsigned long long)cb;
        const unsigned cout = (unsigned)((T < Gw) | (Sw < T));  // chunk carry-out
        const unsigned c_t  = (unsigned)(((Pw ^ Sw) >> lane) & 1ull);
        const unsigned Cm = P ^ (G + GoP + c_t);

        iv4 o;
#pragma unroll
        for (int j = 0; j < 4; ++j) {
            unsigned res = (c[j] + ((Cm >> j) & 1u)) & 0xFFu;
            o[j] = (int)(brev8(res) & (~(unsigned)bv[q][j] & 0xFFu));
        }
        *reinterpret_cast<iv4*>(out + (int)w0 + q * CHUNK + lane * 4) = o;
        cb = cout;
    }
}

extern "C" void kernel_launch(void* const* d_in, const int* in_sizes, int n_in,
                              void* d_out, int out_size, void* d_ws, size_t ws_size,
                              hipStream_t stream) {
    const int* a = (const int*)d_in[0];
    const int* b = (const int*)d_in[1];
    int* out = (int*)d_out;
    const int n = in_sizes[0];                // 67108864
    const int nblk = n / (WTILE * WAVES);     // 8192 blocks

    bss_coal<<<nblk, BLK, 0, stream>>>(a, b, out);
}

// Round 15
// 144.901 us; speedup vs baseline: 1.0489x; 1.0489x over previous
//
#include <hip/hip_runtime.h>

// BSScanThru: out = brev8( (brev8(a) + brev8(b) + carry-chain) mod 256 ) & ~b
//
// FINAL (r13 config): wave-decoupled single pass, perfectly-coalesced.
//
// Geometry: wave tile 1024 elems, split into 4 chunks of 256; in chunk q,
// lane l owns elems q*256 + l*4 .. +3 -> every load/store instruction is
// 64 lanes x 16B contiguous (16 fully-used cache lines per instruction).
//
// Carry-lookahead identity: p_j = (c_j==255) implies g_j = 0, so carry
// into any position = g of the nearest preceding element with c != 255.
// Each wave peeks backward once from its tile base (64-elem window,
// ballot c!=255, g of highest lane; step back on all-propagate, prob
// ~2^-512; idx<0 acts as {c=0,g=0} -> array start needs no special case).
//
// Adder trick (g,p disjoint => carry chain of G+(G|P)+cin IS the gp
// recurrence; carry into bit k = P_k ^ S_k):
//   4-elem group:  Cm = P ^ (G + (G|P) + c_t)      (4-bit masks)
//   wave chunk:    c_t = bit lane of Pw ^ (Gw + (Gw|Pw) + cb)
//   chunk chain:   cb' = carry-out of the 64-bit add (in-register).
//
// Experiment ledger (9 rounds):
//   WIN:  coalesced chunk layout (r13, 150->144.3)
//   NEUT: occupancy 60->80 (r9), sync/LDS removal (r11), SW pipeline (r12),
//         adder-trick scan vs shfl scan (r9)
//   NEG:  nt stores (r7: WRITE +66%), XCD swizzle (r8: FETCH +24%),
//         strided EPT=32 (r10: FETCH +23%), wave tile 2048 (r14: VGPR
//         24->40, occ 79->59%, +5%)
// 144.3 us = 805 MB logical / 5.6 TB/s = 88.5% of the 6.3 TB/s copy
// ceiling with a 2R:1W + scan-dependency stream. WRITE_SIZE at exact
// 256 MiB minimum. Structural floor for this op on MI355X.
//
// Inputs: int32 (values 0..255). Output: int32.

#define BLK 256
#define CHUNK 256            // elems per chunk: 64 lanes x 4
#define NCHUNK 4
#define WTILE (CHUNK * NCHUNK)  // 1024 elems per wave
#define WAVES (BLK / 64)

typedef int iv4 __attribute__((ext_vector_type(4)));

__device__ __forceinline__ unsigned brev8(unsigned x) {
    return __brev(x) >> 24;
}

__global__ __launch_bounds__(BLK) void bss_coal(const int* __restrict__ a,
                                                const int* __restrict__ b,
                                                int* __restrict__ out) {
    const int tid = threadIdx.x;
    const int lane = tid & 63;
    const int wid = tid >> 6;
    const long w0 = ((long)blockIdx.x * WAVES + wid) * WTILE;  // wave tile base

    // ---- main tile loads issued FIRST: 8 perfectly-contiguous dwordx4 ----
    iv4 av[NCHUNK], bv[NCHUNK];
#pragma unroll
    for (int q = 0; q < NCHUNK; ++q) {
        const int off = (int)w0 + q * CHUNK + lane * 4;
        av[q] = *reinterpret_cast<const iv4*>(a + off);
        bv[q] = *reinterpret_cast<const iv4*>(b + off);
    }

    // ---- wave carry-in via backward peek ----
    unsigned cb = 0u;
    {
        long w = w0 - 64;
        for (;;) {
            long idx = w + lane;
            unsigned cc = 0u, gg = 0u;   // idx < 0: virtual non-propagating, g=0
            if (idx >= 0) {
                unsigned s = brev8((unsigned)a[idx]) + brev8((unsigned)b[idx]);
                cc = s & 0xFFu;
                gg = s >> 8;
            }
            unsigned long long m = __ballot(cc != 0xFFu);
            if (m) {
                int hi = 63 - __clzll(m);        // nearest to tile base
                cb = (unsigned)__shfl((int)gg, hi, 64);
                break;
            }
            w -= 64;
        }
    }

    // ---- 4 chunks, carry chained in-register across ballot-adder chains ----
#pragma unroll
    for (int q = 0; q < NCHUNK; ++q) {
        unsigned c[4], G = 0u, P = 0u;
#pragma unroll
        for (int j = 0; j < 4; ++j) {
            unsigned s = brev8((unsigned)av[q][j]) + brev8((unsigned)bv[q][j]);
            c[j] = s & 0xFFu;
            G |= (s >> 8) << j;               // carry generated
            P |= ((c[j] + 1u) >> 8) << j;     // 1 iff c[j]==255
        }
        const unsigned GoP = G | P;
        const unsigned g_t = (G + GoP) >> 4;            // 4-elem carry-out (cin=0)
        const unsigned p_t = (P == 0xFu) ? 1u : 0u;

        const unsigned long long Gw = __ballot(g_t != 0u);
        const unsigned long long Pw = __ballot(p_t != 0u);
        const unsigned long long T  = Gw + (Gw | Pw);
        const unsigned long long Sw = T + (unsigned long long)cb;
        const unsigned cout = (unsigned)((T < Gw) | (Sw < T));  // chunk carry-out
        const unsigned c_t  = (unsigned)(((Pw ^ Sw) >> lane) & 1ull);
        const unsigned Cm = P ^ (G + GoP + c_t);

        iv4 o;
#pragma unroll
        for (int j = 0; j < 4; ++j) {
            unsigned res = (c[j] + ((Cm >> j) & 1u)) & 0xFFu;
            o[j] = (int)(brev8(res) & (~(unsigned)bv[q][j] & 0xFFu));
        }
        *reinterpret_cast<iv4*>(out + (int)w0 + q * CHUNK + lane * 4) = o;
        cb = cout;
    }
}

extern "C" void kernel_launch(void* const* d_in, const int* in_sizes, int n_in,
                              void* d_out, int out_size, void* d_ws, size_t ws_size,
                              hipStream_t stream) {
    const int* a = (const int*)d_in[0];
    const int* b = (const int*)d_in[1];
    int* out = (int*)d_out;
    const int n = in_sizes[0];                // 67108864
    const int nblk = n / (WTILE * WAVES);     // 16384 blocks

    bss_coal<<<nblk, BLK, 0, stream>>>(a, b, out);
}